// Round 12
// baseline (496.200 us; speedup 1.0000x reference)
//
#include <hip/hip_runtime.h>
#include <hip/hip_bf16.h>

#define T_TOKENS 4096
#define HID 1024
#define FFN_ 4096
#define NE 8
#define MAXROWS 10240
#define MAXTILES 40

typedef unsigned short u16;
typedef __bf16 bf16x8 __attribute__((ext_vector_type(8)));
typedef float f32x4 __attribute__((ext_vector_type(4)));
typedef u16 u16x8 __attribute__((ext_vector_type(8)));

__device__ __forceinline__ u16 f2bf(float f) {
  __hip_bfloat16 h = __float2bfloat16(f);
  return *reinterpret_cast<u16*>(&h);
}

__device__ __forceinline__ void gload16(const void* g, void* l) {
  __builtin_amdgcn_global_load_lds(
      (const __attribute__((address_space(1))) void*)g,
      (__attribute__((address_space(3))) void*)l, 16, 0, 0);
}

#define WAIT_VM2() asm volatile("s_waitcnt vmcnt(2)" ::: "memory")
#define WAIT_VM4() asm volatile("s_waitcnt vmcnt(4)" ::: "memory")
#define WAIT_VM0() asm volatile("s_waitcnt vmcnt(0)" ::: "memory")
#define BARRIER()  asm volatile("s_barrier" ::: "memory")

// ---------------- router + x->bf16 convert (fused) ----------------
__global__ __launch_bounds__(256) void router_kernel(
    const float* __restrict__ x, const float* __restrict__ rw,
    int* __restrict__ sel, float* __restrict__ gsel, u16* __restrict__ xb) {
  int token = blockIdx.x * 4 + (threadIdx.x >> 6);
  int lane = threadIdx.x & 63;
  const float* xr = x + (size_t)token * HID;
  u16* xbr = xb + (size_t)token * HID;
  float acc[8];
#pragma unroll
  for (int e = 0; e < 8; e++) acc[e] = 0.f;
  for (int h = lane; h < HID; h += 64) {
    float xv = xr[h];
    xbr[h] = f2bf(xv);
    float4 r0 = *(const float4*)(rw + h * 8);
    float4 r1 = *(const float4*)(rw + h * 8 + 4);
    acc[0] += xv * r0.x; acc[1] += xv * r0.y; acc[2] += xv * r0.z; acc[3] += xv * r0.w;
    acc[4] += xv * r1.x; acc[5] += xv * r1.y; acc[6] += xv * r1.z; acc[7] += xv * r1.w;
  }
#pragma unroll
  for (int e = 0; e < 8; e++) {
#pragma unroll
    for (int o = 32; o > 0; o >>= 1) acc[e] += __shfl_down(acc[e], o);
  }
  if (lane == 0) {
    float mx = acc[0];
#pragma unroll
    for (int e = 1; e < 8; e++) mx = fmaxf(mx, acc[e]);
    float p[8], s = 0.f;
#pragma unroll
    for (int e = 0; e < 8; e++) { p[e] = expf(acc[e] - mx); s += p[e]; }
    float v0 = -1.f; int i0 = 0;
#pragma unroll
    for (int e = 0; e < 8; e++) if (p[e] > v0) { v0 = p[e]; i0 = e; }
    float v1 = -1.f; int i1 = 0;
#pragma unroll
    for (int e = 0; e < 8; e++) if (e != i0 && p[e] > v1) { v1 = p[e]; i1 = e; }
    float inv = 1.f / s;
    sel[token * 2] = i0;     gsel[token * 2] = v0 * inv;
    sel[token * 2 + 1] = i1; gsel[token * 2 + 1] = v1 * inv;
  }
}

// ---------------- hist + fill (fused), 256-row expert padding ----------------
__global__ __launch_bounds__(256) void hist_fill_kernel(
    const int* __restrict__ sel, int* __restrict__ counts,
    int* __restrict__ perm, float* __restrict__ grow) {
  __shared__ int lc[NE];
  if (threadIdx.x < NE) lc[threadIdx.x] = 0;
  __syncthreads();
  int gid = blockIdx.x * 256 + threadIdx.x;
  if (gid < T_TOKENS * 2) atomicAdd(&lc[sel[gid]], 1);
  if (gid < MAXROWS) { perm[gid] = -1; grow[gid] = 0.f; }
  __syncthreads();
  if (threadIdx.x < NE && lc[threadIdx.x] > 0)
    atomicAdd(&counts[threadIdx.x], lc[threadIdx.x]);
}

__global__ void base_kernel(const int* __restrict__ counts, int* __restrict__ cursor,
                            int* __restrict__ tilemap) {
  if (threadIdx.x == 0) {
    int base = 0;
    for (int e = 0; e < NE; e++) {
      cursor[e] = base;
      int padded = (base + counts[e] + 255) & ~255;
      for (int t = base >> 8; t < (padded >> 8); t++) tilemap[t] = e;
      base = padded;
    }
    for (int t = base >> 8; t < MAXTILES; t++) tilemap[t] = 0;
  }
}

__global__ __launch_bounds__(256) void scatter_kernel(
    const int* __restrict__ sel, const float* __restrict__ gsel,
    int* __restrict__ cursor, int* __restrict__ perm, float* __restrict__ grow) {
  int p = blockIdx.x * 256 + threadIdx.x;
  int e = sel[p];
  int pos = atomicAdd(&cursor[e], 1);
  perm[pos] = p >> 1;
  grow[pos] = gsel[p];
}

// ---------------- W1 [1024][32768] -> w1t [32768][1024] bf16 ----------------
__global__ __launch_bounds__(256) void transpose_w1(const float* __restrict__ w1, u16* __restrict__ w1t) {
  __shared__ float tile[64][65];
  int c0 = blockIdx.x * 64;
  int r0 = blockIdx.y * 64;
  int t = threadIdx.x;
  int ci = (t & 15) * 4;
  int ri = t >> 4;
#pragma unroll
  for (int rr = 0; rr < 64; rr += 16) {
    float4 v = *(const float4*)(w1 + (size_t)(r0 + ri + rr) * 32768 + c0 + ci);
    tile[ri + rr][ci] = v.x; tile[ri + rr][ci + 1] = v.y;
    tile[ri + rr][ci + 2] = v.z; tile[ri + rr][ci + 3] = v.w;
  }
  __syncthreads();
  int j = t >> 2;
  int q = t & 3;
  u16x8 o0, o1;
#pragma unroll
  for (int k = 0; k < 8; k++) o0[k] = f2bf(tile[q * 16 + k][j]);
#pragma unroll
  for (int k = 0; k < 8; k++) o1[k] = f2bf(tile[q * 16 + 8 + k][j]);
  u16* dst = w1t + (size_t)(c0 + j) * 1024 + r0 + q * 16;
  *(u16x8*)dst = o0;
  *(u16x8*)(dst + 8) = o1;
}

// ---------------- W2 [32768][1024] -> w2t [e][1024][4096] bf16 ----------------
__global__ __launch_bounds__(256) void transpose_w2(const float* __restrict__ w2, u16* __restrict__ w2t) {
  __shared__ float tile[64][65];
  int fb = blockIdx.x;
  int h0 = blockIdx.y * 64;
  int e = fb >> 6;
  int f0 = (fb & 63) * 64;
  int t = threadIdx.x;
  int ci = (t & 15) * 4;
  int ri = t >> 4;
#pragma unroll
  for (int rr = 0; rr < 64; rr += 16) {
    float4 v = *(const float4*)(w2 + (size_t)(fb * 64 + ri + rr) * 1024 + h0 + ci);
    tile[ri + rr][ci] = v.x; tile[ri + rr][ci + 1] = v.y;
    tile[ri + rr][ci + 2] = v.z; tile[ri + rr][ci + 3] = v.w;
  }
  __syncthreads();
  int j = t >> 2;
  int q = t & 3;
  u16x8 o0, o1;
#pragma unroll
  for (int k = 0; k < 8; k++) o0[k] = f2bf(tile[q * 16 + k][j]);
#pragma unroll
  for (int k = 0; k < 8; k++) o1[k] = f2bf(tile[q * 16 + 8 + k][j]);
  u16* dst = w2t + (size_t)e * 4194304 + (size_t)(h0 + j) * 4096 + f0 + q * 16;
  *(u16x8*)dst = o0;
  *(u16x8*)(dst + 8) = o1;
}

// ======== GEMM1: 256x256, BK=64, 8 waves (2Mx4N), 4-phase/K-tile counted-vmcnt ========
// Stage order per tile: B0,B1,Apair0,Apair1 -> vmcnt(2)@ph0, vmcnt(4)@ph2, never 0.
__global__ __launch_bounds__(512, 1) void gemm1_kernel(
    const u16* __restrict__ xb, const u16* __restrict__ w1t,
    const int* __restrict__ perm, const float* __restrict__ grow,
    const int* __restrict__ tilemap, u16* __restrict__ hbuf,
    const u16* __restrict__ zp) {
  int bid = blockIdx.x;                 // 0..639 = 8 xcd * 80
  int xcd = bid & 7, pos = bid >> 3;    // 0..79
  int nt = pos / 5;                     // 0..15 (slow)
  int mt = xcd * 5 + (pos - nt * 5);    // mt fastest
  int e = tilemap[mt];
  int row0 = mt * 256;
  int t = threadIdx.x, lane = t & 63, wave = t >> 6;
  __shared__ u16 As[2][256 * 64], Bs[2][256 * 64];   // 128 KB

  int trow = t >> 3;                    // 0..63
  int cs = (t & 7) ^ (trow & 7);        // swizzled 16B chunk (row offsets are %8==0)
  const u16* asrc[4]; int astep[4];
  const u16* bsrc[4];
#pragma unroll
  for (int i = 0; i < 4; i++) {
    int row = i * 64 + trow;
    int tok = perm[row0 + row];
    if (tok >= 0) { asrc[i] = xb + (size_t)tok * 1024 + cs * 8; astep[i] = 64; }
    else { asrc[i] = zp + cs * 8; astep[i] = 0; }
    bsrc[i] = w1t + (size_t)e * 4194304 + (size_t)(nt * 256 + row) * 1024 + cs * 8;
  }

  f32x4 acc[8][4] = {};
  bf16x8 bq[4][2];
  int r = lane & 15, kg = lane >> 4;
  int wm = wave >> 2, wn = wave & 3;    // 2M x 4N

  auto stageB = [&](int d, int half) {
    char* base = (char*)&Bs[d][0] + half * 16384;
    gload16(bsrc[half * 2], base + t * 16);
    gload16(bsrc[half * 2 + 1], base + 8192 + t * 16);
  };
  auto stageA = [&](int d, int pair) {  // pair0: C0,C2 ; pair1: C1,C3
    char* base = (char*)&As[d][0];
    if (pair == 0) {
      gload16(asrc[0], base + t * 16);
      gload16(asrc[2], base + 16384 + t * 16);
    } else {
      gload16(asrc[1], base + 8192 + t * 16);
      gload16(asrc[3], base + 24576 + t * 16);
    }
  };
  auto adv = [&]() {
#pragma unroll
    for (int i = 0; i < 4; i++) { asrc[i] += astep[i]; bsrc[i] += 64; }
  };
  auto readB = [&](int d) {
    const char* Bb = (const char*)&Bs[d][0];
#pragma unroll
    for (int ni = 0; ni < 4; ni++)
#pragma unroll
      for (int kk = 0; kk < 2; kk++) {
        int rr = wn * 64 + ni * 16 + r;
        bq[ni][kk] = *(const bf16x8*)(Bb + rr * 128 + ((kk * 64 + kg * 16) ^ ((rr & 7) << 4)));
      }
  };
  auto phase = [&](int d, int q) {      // A-rows mi=2q,2q+1 ; 16 MFMA
    const char* Ab = (const char*)&As[d][0];
    bf16x8 af[2][2];
#pragma unroll
    for (int m2 = 0; m2 < 2; m2++)
#pragma unroll
      for (int kk = 0; kk < 2; kk++) {
        int rr = wm * 128 + (q * 2 + m2) * 16 + r;
        af[m2][kk] = *(const bf16x8*)(Ab + rr * 128 + ((kk * 64 + kg * 16) ^ ((rr & 7) << 4)));
      }
    __builtin_amdgcn_s_setprio(1);
#pragma unroll
    for (int m2 = 0; m2 < 2; m2++)
#pragma unroll
      for (int ni = 0; ni < 4; ni++)
#pragma unroll
        for (int kk = 0; kk < 2; kk++)
          acc[q * 2 + m2][ni] = __builtin_amdgcn_mfma_f32_16x16x32_bf16(af[m2][kk], bq[ni][kk], acc[q * 2 + m2][ni], 0, 0, 0);
    __builtin_amdgcn_s_setprio(0);
  };

  // prologue: tile 0, order B0,B1,A0,A1
  stageB(0, 0); stageB(0, 1); stageA(0, 0); stageA(0, 1);
  adv();
  for (int kt = 0; kt < 16; kt++) {
    int d = kt & 1;
    bool st = kt < 15;
    WAIT_VM2(); BARRIER();
    readB(d);
    if (st) stageB(d ^ 1, 0);
    phase(d, 0);
    BARRIER();
    if (st) stageB(d ^ 1, 1);
    phase(d, 1);
    BARRIER();
    if (kt == 15) { WAIT_VM0(); } else { WAIT_VM4(); }
    BARRIER();
    if (st) stageA(d ^ 1, 0);
    phase(d, 2);
    BARRIER();
    if (st) stageA(d ^ 1, 1);
    phase(d, 3);
    if (st) adv();
    BARRIER();
  }

  // epilogue: gate * gelu -> bf16
#pragma unroll
  for (int mi = 0; mi < 8; mi++) {
    int rl = wm * 128 + mi * 16 + kg * 4;
#pragma unroll
    for (int j = 0; j < 4; j++) {
      float gv = grow[row0 + rl + j];
#pragma unroll
      for (int ni = 0; ni < 4; ni++) {
        int col = nt * 256 + wn * 64 + ni * 16 + r;
        float v = acc[mi][ni][j];
        float ge = 0.5f * v * (1.0f + erff(v * 0.7071067811865475f)) * gv;
        hbuf[(size_t)(row0 + rl + j) * 4096 + col] = f2bf(ge);
      }
    }
  }
}

// ======== GEMM2: same schedule, split-K=4, atomic combine ========
__global__ __launch_bounds__(512, 1) void gemm2_kernel(
    const u16* __restrict__ hbuf, const u16* __restrict__ w2t,
    const int* __restrict__ perm, const int* __restrict__ tilemap,
    float* __restrict__ out) {
  int bid = blockIdx.x;                 // 0..639
  int xcd = bid & 7, pos = bid >> 3;    // 0..79
  int c16 = pos / 5;                    // 0..15: ksp,nt
  int mt = xcd * 5 + (pos - c16 * 5);   // mt fastest
  int ksp = c16 >> 2;                   // 0..3, K=1024 each
  int nt = c16 & 3;                     // 0..3, 256 out-cols
  int e = tilemap[mt];
  int row0 = mt * 256;
  int t = threadIdx.x, lane = t & 63, wave = t >> 6;
  __shared__ u16 As[2][256 * 64], Bs[2][256 * 64];

  int trow = t >> 3;
  int cs = (t & 7) ^ (trow & 7);
  const u16* asrc[4];
  const u16* bsrc[4];
#pragma unroll
  for (int i = 0; i < 4; i++) {
    int row = i * 64 + trow;
    asrc[i] = hbuf + (size_t)(row0 + row) * 4096 + (size_t)ksp * 1024 + cs * 8;
    bsrc[i] = w2t + (size_t)e * 4194304 + (size_t)(nt * 256 + row) * 4096 + (size_t)ksp * 1024 + cs * 8;
  }

  f32x4 acc[8][4] = {};
  bf16x8 bq[4][2];
  int r = lane & 15, kg = lane >> 4;
  int wm = wave >> 2, wn = wave & 3;

  auto stageB = [&](int d, int half) {
    char* base = (char*)&Bs[d][0] + half * 16384;
    gload16(bsrc[half * 2], base + t * 16);
    gload16(bsrc[half * 2 + 1], base + 8192 + t * 16);
  };
  auto stageA = [&](int d, int pair) {
    char* base = (char*)&As[d][0];
    if (pair == 0) {
      gload16(asrc[0], base + t * 16);
      gload16(asrc[2], base + 16384 + t * 16);
    } else {
      gload16(asrc[1], base + 8192 + t * 16);
      gload16(asrc[3], base + 24576 + t * 16);
    }
  };
  auto adv = [&]() {
#pragma unroll
    for (int i = 0; i < 4; i++) { asrc[i] += 64; bsrc[i] += 64; }
  };
  auto readB = [&](int d) {
    const char* Bb = (const char*)&Bs[d][0];
#pragma unroll
    for (int ni = 0; ni < 4; ni++)
#pragma unroll
      for (int kk = 0; kk < 2; kk++) {
        int rr = wn * 64 + ni * 16 + r;
        bq[ni][kk] = *(const bf16x8*)(Bb + rr * 128 + ((kk * 64 + kg * 16) ^ ((rr & 7) << 4)));
      }
  };
  auto phase = [&](int d, int q) {
    const char* Ab = (const char*)&As[d][0];
    bf16x8 af[2][2];
#pragma unroll
    for (int m2 = 0; m2 < 2; m2++)
#pragma unroll
      for (int kk = 0; kk < 2; kk++) {
        int rr = wm * 128 + (q * 2 + m2) * 16 + r;
        af[m2][kk] = *(const bf16x8*)(Ab + rr * 128 + ((kk * 64 + kg * 16) ^ ((rr & 7) << 4)));
      }
    __builtin_amdgcn_s_setprio(1);
#pragma unroll
    for (int m2 = 0; m2 < 2; m2++)
#pragma unroll
      for (int ni = 0; ni < 4; ni++)
#pragma unroll
        for (int kk = 0; kk < 2; kk++)
          acc[q * 2 + m2][ni] = __builtin_amdgcn_mfma_f32_16x16x32_bf16(af[m2][kk], bq[ni][kk], acc[q * 2 + m2][ni], 0, 0, 0);
    __builtin_amdgcn_s_setprio(0);
  };

  stageB(0, 0); stageB(0, 1); stageA(0, 0); stageA(0, 1);
  adv();
  for (int kt = 0; kt < 16; kt++) {
    int d = kt & 1;
    bool st = kt < 15;
    WAIT_VM2(); BARRIER();
    readB(d);
    if (st) stageB(d ^ 1, 0);
    phase(d, 0);
    BARRIER();
    if (st) stageB(d ^ 1, 1);
    phase(d, 1);
    BARRIER();
    if (kt == 15) { WAIT_VM0(); } else { WAIT_VM4(); }
    BARRIER();
    if (st) stageA(d ^ 1, 0);
    phase(d, 2);
    BARRIER();
    if (st) stageA(d ^ 1, 1);
    phase(d, 3);
    if (st) adv();
    BARRIER();
  }

#pragma unroll
  for (int mi = 0; mi < 8; mi++) {
    int rl = wm * 128 + mi * 16 + kg * 4;
#pragma unroll
    for (int j = 0; j < 4; j++) {
      int tok = perm[row0 + rl + j];
      if (tok >= 0) {
#pragma unroll
        for (int ni = 0; ni < 4; ni++) {
          int col = nt * 256 + wn * 64 + ni * 16 + r;
          atomicAdd(out + (size_t)tok * 1024 + col, acc[mi][ni][j]);
        }
      }
    }
  }
}

extern "C" void kernel_launch(void* const* d_in, const int* in_sizes, int n_in,
                              void* d_out, int out_size, void* d_ws, size_t ws_size,
                              hipStream_t stream) {
  const float* x  = (const float*)d_in[0];
  const float* rw = (const float*)d_in[1];
  const float* w1 = (const float*)d_in[2];
  const float* w2 = (const float*)d_in[3];
  float* out = (float*)d_out;
  char* ws = (char*)d_ws;

  size_t off = 0;
  auto take = [&](size_t n) { char* p = ws + off; off += (n + 255) & ~255ull; return p; };
  u16* w1t   = (u16*)take(8ull * 4096 * 1024 * 2);
  u16* w2t   = (u16*)take(8ull * 4096 * 1024 * 2);
  u16* xb    = (u16*)take((size_t)T_TOKENS * HID * 2);
  u16* hbuf  = (u16*)take((size_t)MAXROWS * FFN_ * 2);
  int* sel   = (int*)take(T_TOKENS * 2 * 4);
  float* gsel = (float*)take(T_TOKENS * 2 * 4);
  int* perm  = (int*)take(MAXROWS * 4);
  float* grow = (float*)take(MAXROWS * 4);
  int* tmap  = (int*)take(MAXTILES * 4);
  int* counts = (int*)take(NE * 4);
  int* cursor = (int*)take(NE * 4);
  u16* zp    = (u16*)take(4096);

  hipMemsetAsync(zp, 0, 4096, stream);
  hipMemsetAsync(counts, 0, NE * 4, stream);
  hipMemsetAsync(out, 0, (size_t)T_TOKENS * HID * 4, stream);

  transpose_w1<<<dim3(512, 16), 256, 0, stream>>>(w1, w1t);
  transpose_w2<<<dim3(512, 16), 256, 0, stream>>>(w2, w2t);
  router_kernel<<<dim3(T_TOKENS / 4), 256, 0, stream>>>(x, rw, sel, gsel, xb);
  hist_fill_kernel<<<dim3(MAXROWS / 256), 256, 0, stream>>>(sel, counts, perm, grow);
  base_kernel<<<dim3(1), 64, 0, stream>>>(counts, cursor, tmap);
  scatter_kernel<<<dim3(T_TOKENS * 2 / 256), 256, 0, stream>>>(sel, gsel, cursor, perm, grow);
  gemm1_kernel<<<dim3(640), 512, 0, stream>>>(xb, w1t, perm, grow, tmap, hbuf, zp);
  gemm2_kernel<<<dim3(640), 512, 0, stream>>>(hbuf, w2t, perm, tmap, out);
}